// Round 23
// baseline (304.404 us; speedup 1.0000x reference)
//
#include <hip/hip_runtime.h>
#include <hip/hip_bf16.h>
#include <math.h>

#define N_NODES 50000
#define N_EDGES 800000
#define BN_EPS  1e-5f
#define SCAN_NB 49     // ceil(50000/1024)
#define AGG_NB  2048   // agg grid blocks

typedef float floatx2 __attribute__((ext_vector_type(2)));
typedef _Float16 half8 __attribute__((ext_vector_type(8)));
typedef float f32x4 __attribute__((ext_vector_type(4)));

// ---- workspace layout (float-element offsets) ----
#define OFS_RELW   0                    // 200*128 padded relw
#define OFS_KH     25600                // 50000*32 uints (fp8 rows, 128B)
#define OFS_Q      1625600              // 50000*128 padded q
#define OFS_VH     8025600              // 50000*32 uints
#define OFS_ATTP   9625600
#define OFS_BNPART 10425600             // 200 * AGG_NB
#define OFS_BNSC   10835200
#define OFS_BNSH   10835328
#define OFS_CNT    10835456
#define OFS_PART   10885632
#define OFS_BSUM   10935808
#define OFS_OFFS   10935872
#define OFS_CURS   10986048
#define OFS_PEDGE  11036224             // 800000 x uint64: src|ety<<17|dst<<32
#define OFS_WH     12636224             // 4*112*128 f16 padded W = 28672 floats
#define WS_ELEMS   12664896

// rel_w[r][c] (padded to 128 cols, zero pad)
__global__ __launch_bounds__(256) void relw_kernel(
    const float* __restrict__ wcomp, const float* __restrict__ ratt,
    float* __restrict__ relw)
{
    int o = blockIdx.x * 256 + threadIdx.x;
    if (o >= 200 * 128) return;
    int r = o / 128, c = o % 128;
    float acc = 0.f;
    if (c < 100) {
        #pragma unroll 10
        for (int b = 0; b < 50; ++b) acc += wcomp[r * 50 + b] * ratt[b * 100 + c];
    }
    relw[o] = acc;
}

// W -> f16, [m][col(112 pad)][k(128 pad)]; pads zero. Wm[c][k] row-major as-is.
__global__ __launch_bounds__(256) void wbh_kernel(
    const float* __restrict__ Wk, const float* __restrict__ Wq,
    const float* __restrict__ Wv, const float* __restrict__ Ws,
    _Float16* __restrict__ Wh)
{
    int o = blockIdx.x * 256 + threadIdx.x;
    if (o >= 4 * 112 * 128) return;
    int m = o / 14336, rem = o % 14336, r = rem / 128, k = rem % 128;
    const float* W = (m == 0) ? Wk : (m == 1) ? Wq : (m == 2) ? Wv : Ws;
    float v = (r < 100 && k < 100) ? W[r * 100 + k] : 0.f;
    Wh[o] = (_Float16)v;
}

// fused projections via MFMA (f16 16x16x32), slim version:
//  - X tile staged in LDS, A-fragments hoisted to registers, then the LDS
//    buffer is reused (union) for the f32 acc transpose -> 29.7 KB LDS,
//    5 blocks/CU (20 waves).
//  - B-fragments read per-mfma DIRECTLY from global Wh (28.6 KB/matrix,
//    L2-resident across all blocks) -> no W staging, no wb conflicts.
// Wave w: rows 16w..16w+15; 7 col-tiles x 4 K-steps = 28 mfma.
// Epilogue: coalesced bias + fp8/f32 pack from sm.acc.
__global__ __launch_bounds__(256, 4) void proj_kernel(
    const float* __restrict__ X, const _Float16* __restrict__ Wh,
    const float* __restrict__ bk, const float* __restrict__ bq,
    const float* __restrict__ bv, const float* __restrict__ bs,
    unsigned* __restrict__ khp, float* __restrict__ qo,
    unsigned* __restrict__ vhp, float* __restrict__ so)
{
    __shared__ union {
        _Float16 xb[64][136];   // 17.4 KB
        float acc[64][116];     // 29.7 KB (reused after A-frag hoist)
    } sm;

    const int tid = threadIdx.x;
    const int nb  = blockIdx.x * 64;
    const int m   = blockIdx.y;
    const float* bp = (m == 0) ? bk : (m == 1) ? bq : (m == 2) ? bv : bs;

    // stage X as f16: 64 nodes x 32 k-quads (k>=100 -> 0)
    for (int idx = tid; idx < 64 * 32; idx += 256) {
        int n = idx >> 5, kq = idx & 31;
        int node = nb + n;
        float4 x = (node < N_NODES && kq < 25)
                   ? ((const float4*)(X + (size_t)node * 100))[kq]
                   : make_float4(0.f, 0.f, 0.f, 0.f);
        _Float16 h[4] = {(_Float16)x.x, (_Float16)x.y, (_Float16)x.z, (_Float16)x.w};
        *(ushort4*)&sm.xb[n][4 * kq] = *(const ushort4*)h;
    }
    __syncthreads();

    const int w = tid >> 6;
    const int l = tid & 63;
    const int rsel = l & 15;          // A row / B col within tile
    const int kb   = (l >> 4) * 8;    // k base for this lane

    half8 afr[4];
    #pragma unroll
    for (int kk = 0; kk < 4; ++kk)
        afr[kk] = *(const half8*)&sm.xb[16 * w + rsel][kk * 32 + kb];
    __syncthreads();   // all waves have A-frags; xb space now reusable

    f32x4 acc[7];
    #pragma unroll
    for (int t = 0; t < 7; ++t) acc[t] = (f32x4){0.f, 0.f, 0.f, 0.f};

    const _Float16* wg = Wh + (size_t)m * 14336;
    #pragma unroll
    for (int t = 0; t < 7; ++t) {
        #pragma unroll
        for (int kk = 0; kk < 4; ++kk) {
            const half8 bfr = *(const half8*)(wg + (16 * t + rsel) * 128 + kk * 32 + kb);
            acc[t] = __builtin_amdgcn_mfma_f32_16x16x32_f16(afr[kk], bfr, acc[t], 0, 0, 0);
        }
    }

    // dump acc: lane l holds rows 16w+(l>>4)*4+r, col 16t+(l&15)
    const int drow0 = 16 * w + (l >> 4) * 4;
    #pragma unroll
    for (int t = 0; t < 7; ++t)
        #pragma unroll
        for (int r = 0; r < 4; ++r)
            sm.acc[drow0 + r][16 * t + rsel] = acc[t][r];
    __syncthreads();

    // epilogue: 64 nodes x 32 col-quads, coalesced
    for (int idx = tid; idx < 64 * 32; idx += 256) {
        int n = idx >> 5, cq = idx & 31;
        int node = nb + n;
        if (node >= N_NODES) continue;
        float4 v = (cq < 28) ? *(const float4*)&sm.acc[n][4 * cq]
                             : make_float4(0.f, 0.f, 0.f, 0.f);
        float4 bb = (cq < 25) ? *(const float4*)(bp + 4 * cq)
                              : make_float4(0.f, 0.f, 0.f, 0.f);
        v.x += bb.x; v.y += bb.y; v.z += bb.z; v.w += bb.w;
        if (m == 0 || m == 2) {
            unsigned* oph = (m == 0) ? khp : vhp;
            int wd = 0;
            wd = __builtin_amdgcn_cvt_pk_fp8_f32(v.x, v.y, wd, false);
            wd = __builtin_amdgcn_cvt_pk_fp8_f32(v.z, v.w, wd, true);
            oph[(size_t)node * 32 + cq] = (unsigned)wd;
        } else if (m == 1) {
            *(float4*)(qo + (size_t)node * 128 + 4 * cq) = v;
        } else {
            if (cq < 25)
                *(float4*)(so + (size_t)node * 100 + 4 * cq) = v;
        }
    }
}

__global__ __launch_bounds__(256) void hist_kernel(
    const int* __restrict__ dst, int* __restrict__ cnt)
{
    int e = blockIdx.x * 256 + threadIdx.x;
    if (e < N_EDGES) atomicAdd(&cnt[dst[e]], 1);
}

__global__ __launch_bounds__(1024) void scanA_kernel(
    const int* __restrict__ cnt, int* __restrict__ partial, int* __restrict__ bsum)
{
    __shared__ int buf[1024];
    int tid = threadIdx.x;
    int i = blockIdx.x * 1024 + tid;
    int val = (i < N_NODES) ? cnt[i] : 0;
    buf[tid] = val;
    __syncthreads();
    for (int off = 1; off < 1024; off <<= 1) {
        int t = (tid >= off) ? buf[tid - off] : 0;
        __syncthreads();
        buf[tid] += t;
        __syncthreads();
    }
    int incl = buf[tid];
    if (i < N_NODES) partial[i] = incl - val;
    if (tid == 1023) bsum[blockIdx.x] = incl;
}

__global__ __launch_bounds__(1024) void scanB_kernel(
    const int* __restrict__ partial, const int* __restrict__ bsum,
    int* __restrict__ offs)
{
    __shared__ int bs[64];
    int tid = threadIdx.x;
    if (tid < SCAN_NB) bs[tid] = bsum[tid];
    __syncthreads();
    if (tid == 0) {
        int run = 0;
        for (int b = 0; b < SCAN_NB; ++b) { int t = bs[b]; bs[b] = run; run += t; }
    }
    __syncthreads();
    for (int i = tid; i < N_NODES; i += 1024) offs[i] = partial[i] + bs[i >> 10];
    if (tid == 0) offs[N_NODES] = N_EDGES;
}

// scatter ONE packed 8B word per edge: src | ety<<17 | dst<<32
__global__ __launch_bounds__(256) void scatter_kernel(
    const int* __restrict__ src, const int* __restrict__ dst,
    const int* __restrict__ ety, const int* __restrict__ offs,
    int* __restrict__ cursor, unsigned long long* __restrict__ pedge)
{
    int e = blockIdx.x * 256 + threadIdx.x;
    if (e >= N_EDGES) return;
    int d = dst[e];
    int p = atomicAdd(&cursor[d], 1);
    pedge[offs[d] + p] = (unsigned long long)(unsigned)src[e]
                       | ((unsigned long long)(unsigned)ety[e] << 17)
                       | ((unsigned long long)(unsigned)d << 32);
}

// attention logits: 16 lanes/edge on padded-128 rows; 4 edges/wave.
__global__ __launch_bounds__(256) void attp_kernel(
    const unsigned* __restrict__ khp, const float* __restrict__ q,
    const float* __restrict__ relw,
    const unsigned long long* __restrict__ pedge, float* __restrict__ attp)
{
    const int lane = threadIdx.x & 15;
    const int i = blockIdx.x * 16 + (threadIdx.x >> 4);
    if (i >= N_EDGES) return;
    const unsigned long long pw = pedge[i];
    const int s_ = (int)(pw & 0x1FFFFull);
    const int t_ = (int)((pw >> 17) & 0x7FFFull);
    const int d_ = (int)(pw >> 32);

    const unsigned* kr = khp + (size_t)s_ * 32;
    const float4*   qr = (const float4*)(q + (size_t)d_ * 128);
    const float4*   wr = (const float4*)(relw + t_ * 128);

    const unsigned kw0 = kr[lane];
    const unsigned kw1 = kr[lane + 16];
    const float4 qv0 = qr[lane];
    const float4 qv1 = qr[lane + 16];
    const float4 wv0 = wr[lane];
    const float4 wv1 = wr[lane + 16];

    const floatx2 ka = __builtin_amdgcn_cvt_pk_f32_fp8((int)kw0, false);
    const floatx2 kb = __builtin_amdgcn_cvt_pk_f32_fp8((int)kw0, true);
    const floatx2 kc = __builtin_amdgcn_cvt_pk_f32_fp8((int)kw1, false);
    const floatx2 kd = __builtin_amdgcn_cvt_pk_f32_fp8((int)kw1, true);

    float acc = ka[0] * wv0.x * qv0.x + ka[1] * wv0.y * qv0.y
              + kb[0] * wv0.z * qv0.z + kb[1] * wv0.w * qv0.w
              + kc[0] * wv1.x * qv1.x + kc[1] * wv1.y * qv1.y
              + kd[0] * wv1.z * qv1.z + kd[1] * wv1.w * qv1.w;

    #pragma unroll
    for (int off = 8; off > 0; off >>= 1) acc += __shfl_xor(acc, off, 16);
    if (lane == 0) attp[i] = acc;
}

// one wave per node: softmax + weighted-V aggregate (v fp8) + gated combine
// + BN partials. src read from low word of pedge.
__global__ __launch_bounds__(256) void agg_kernel(
    const int* __restrict__ offs, const unsigned* __restrict__ pedge32,
    const float* __restrict__ attp, const unsigned short* __restrict__ vhp,
    const float* __restrict__ alpha, float* __restrict__ out,
    float* __restrict__ bnpart)
{
    __shared__ float ls[100], lq[100];
    const int tid = threadIdx.x;
    if (tid < 100) { ls[tid] = 0.f; lq[tid] = 0.f; }
    __syncthreads();
    const int lane = tid & 63;
    const int gwave = blockIdx.x * 4 + (tid >> 6);
    const int nwaves = AGG_NB * 4;
    const float a = 1.f / (1.f + __expf(-alpha[0]));
    const float b = 1.f - a;
    const int cl = lane;             // lane owns columns 2cl, 2cl+1
    const bool act = (cl < 50);
    float sx = 0.f, sy = 0.f, qx = 0.f, qy = 0.f;

    for (int n = gwave; n < N_NODES; n += nwaves) {
        const int beg = offs[n], end = offs[n + 1];
        float m = -INFINITY;
        for (int i = beg + lane; i < end; i += 64) m = fmaxf(m, attp[i]);
        #pragma unroll
        for (int off = 32; off > 0; off >>= 1) m = fmaxf(m, __shfl_xor(m, off, 64));
        float ax = 0.f, ay = 0.f, wsum = 0.f;
        int i = beg;
        for (; i + 4 <= end; i += 4) {
            const int s0 = (int)(pedge32[2 * (i)]     & 0x1FFFFu);
            const int s1 = (int)(pedge32[2 * (i + 1)] & 0x1FFFFu);
            const int s2 = (int)(pedge32[2 * (i + 2)] & 0x1FFFFu);
            const int s3 = (int)(pedge32[2 * (i + 3)] & 0x1FFFFu);
            const float w0 = __expf(attp[i] - m),     w1 = __expf(attp[i + 1] - m);
            const float w2 = __expf(attp[i + 2] - m), w3 = __expf(attp[i + 3] - m);
            wsum += w0 + w1 + w2 + w3;
            if (act) {
                const unsigned short h0 = vhp[(size_t)s0 * 64 + cl];
                const unsigned short h1 = vhp[(size_t)s1 * 64 + cl];
                const unsigned short h2 = vhp[(size_t)s2 * 64 + cl];
                const unsigned short h3 = vhp[(size_t)s3 * 64 + cl];
                const floatx2 v0 = __builtin_amdgcn_cvt_pk_f32_fp8((int)h0, false);
                const floatx2 v1 = __builtin_amdgcn_cvt_pk_f32_fp8((int)h1, false);
                const floatx2 v2 = __builtin_amdgcn_cvt_pk_f32_fp8((int)h2, false);
                const floatx2 v3 = __builtin_amdgcn_cvt_pk_f32_fp8((int)h3, false);
                ax += w0 * v0[0] + w1 * v1[0] + w2 * v2[0] + w3 * v3[0];
                ay += w0 * v0[1] + w1 * v1[1] + w2 * v2[1] + w3 * v3[1];
            }
        }
        for (; i < end; ++i) {
            const int s0 = (int)(pedge32[2 * i] & 0x1FFFFu);
            const float w0 = __expf(attp[i] - m);
            wsum += w0;
            if (act) {
                const unsigned short h0 = vhp[(size_t)s0 * 64 + cl];
                const floatx2 v0 = __builtin_amdgcn_cvt_pk_f32_fp8((int)h0, false);
                ax += w0 * v0[0];
                ay += w0 * v0[1];
            }
        }
        const float inv = (wsum > 0.f) ? 1.f / wsum : 0.f;
        if (act) {
            float2* po = (float2*)(out + (size_t)n * 100);
            float2 cur = po[cl];
            float v0 = a * cur.x + b * ax * inv;
            float v1 = a * cur.y + b * ay * inv;
            po[cl] = make_float2(v0, v1);
            sx += v0; qx += v0 * v0;
            sy += v1; qy += v1 * v1;
        }
    }
    if (act) {
        atomicAdd(&ls[2 * cl], sx);     atomicAdd(&ls[2 * cl + 1], sy);
        atomicAdd(&lq[2 * cl], qx);     atomicAdd(&lq[2 * cl + 1], qy);
    }
    __syncthreads();
    if (tid < 100) {
        bnpart[(size_t)tid * AGG_NB + blockIdx.x]         = ls[tid];
        bnpart[(size_t)(tid + 100) * AGG_NB + blockIdx.x] = lq[tid];
    }
}

__global__ __launch_bounds__(256) void bnfin_kernel(
    const float* __restrict__ bnpart,
    const float* __restrict__ gamma, const float* __restrict__ beta,
    float* __restrict__ bnsc, float* __restrict__ bnsh)
{
    const int c = blockIdx.x * 4 + (threadIdx.x >> 6);
    const int lane = threadIdx.x & 63;
    if (c >= 100) return;
    float s = 0.f, q = 0.f;
    for (int b2 = lane; b2 < AGG_NB; b2 += 64) {
        s += bnpart[(size_t)c * AGG_NB + b2];
        q += bnpart[(size_t)(c + 100) * AGG_NB + b2];
    }
    #pragma unroll
    for (int off = 32; off > 0; off >>= 1) {
        s += __shfl_xor(s, off, 64);
        q += __shfl_xor(q, off, 64);
    }
    if (lane == 0) {
        const float inv_n = 1.f / (float)N_NODES;
        float mean = s * inv_n;
        float var = q * inv_n - mean * mean;
        float sc = gamma[c] * rsqrtf(var + BN_EPS);
        bnsc[c] = sc;
        bnsh[c] = beta[c] - mean * sc;
    }
}

__global__ __launch_bounds__(256) void apply_kernel(
    float* __restrict__ out, const float* __restrict__ bnsc,
    const float* __restrict__ bnsh)
{
    const int total4 = N_NODES * 25;
    for (int idx = blockIdx.x * 256 + threadIdx.x; idx < total4; idx += gridDim.x * 256) {
        float4* p = ((float4*)out) + idx;
        const int c = (idx % 25) * 4;
        float4 t = *p;
        t.x = tanhf(t.x * bnsc[c]     + bnsh[c]);
        t.y = tanhf(t.y * bnsc[c + 1] + bnsh[c + 1]);
        t.z = tanhf(t.z * bnsc[c + 2] + bnsh[c + 2]);
        t.w = tanhf(t.w * bnsc[c + 3] + bnsh[c + 3]);
        *p = t;
    }
}

__global__ __launch_bounds__(256) void rout_kernel(
    const float* __restrict__ rf, const float* __restrict__ Wr,
    const float* __restrict__ br, float* __restrict__ out)
{
    int o = blockIdx.x * 256 + threadIdx.x;
    if (o >= 200 * 100) return;
    int r = o / 100, c = o % 100;
    float acc = br[c];
    #pragma unroll 10
    for (int d = 0; d < 100; ++d) acc += rf[r * 100 + d] * Wr[c * 100 + d];
    out[N_NODES * 100 + o] = acc;
}

extern "C" void kernel_launch(void* const* d_in, const int* in_sizes, int n_in,
                              void* d_out, int out_size, void* d_ws, size_t ws_size,
                              hipStream_t stream) {
    const float* X     = (const float*)d_in[0];
    const float* rfeat = (const float*)d_in[1];
    const int*   src   = (const int*)d_in[2];
    const int*   dst   = (const int*)d_in[3];
    const int*   ety   = (const int*)d_in[4];
    const float* Wsw   = (const float*)d_in[6];
    const float* Wsb   = (const float*)d_in[7];
    const float* Wkw   = (const float*)d_in[8];
    const float* Wkb   = (const float*)d_in[9];
    const float* Wqw   = (const float*)d_in[10];
    const float* Wqb   = (const float*)d_in[11];
    const float* Wvw   = (const float*)d_in[12];
    const float* Wvb   = (const float*)d_in[13];
    const float* Wrw   = (const float*)d_in[14];
    const float* Wrb   = (const float*)d_in[15];
    const float* ratt  = (const float*)d_in[16];
    const float* wcomp = (const float*)d_in[17];
    const float* alpha = (const float*)d_in[18];
    const float* gamma = (const float*)d_in[20];
    const float* beta  = (const float*)d_in[21];

    float* out = (float*)d_out;
    float* ws  = (float*)d_ws;
    if (ws_size < (size_t)WS_ELEMS * sizeof(float)) return;

    float* relw          = ws + OFS_RELW;
    unsigned* khp        = (unsigned*)(ws + OFS_KH);
    float* q             = ws + OFS_Q;
    unsigned* vhp        = (unsigned*)(ws + OFS_VH);
    float* attp          = ws + OFS_ATTP;
    float* bnpart        = ws + OFS_BNPART;
    float* bnsc          = ws + OFS_BNSC;
    float* bnsh          = ws + OFS_BNSH;
    _Float16* Wh         = (_Float16*)(ws + OFS_WH);
    int* cnt             = (int*)(ws + OFS_CNT);
    int* partial         = (int*)(ws + OFS_PART);
    int* bsum            = (int*)(ws + OFS_BSUM);
    int* offs            = (int*)(ws + OFS_OFFS);
    int* cursor          = (int*)(ws + OFS_CURS);
    unsigned long long* pedge = (unsigned long long*)(ws + OFS_PEDGE);

    hipMemsetAsync(cnt, 0, 50000 * sizeof(int), stream);
    hipMemsetAsync(cursor, 0, 50000 * sizeof(int), stream);

    relw_kernel<<<(200 * 128 + 255) / 256, 256, 0, stream>>>(wcomp, ratt, relw);
    wbh_kernel<<<(4 * 112 * 128 + 255) / 256, 256, 0, stream>>>(
        Wkw, Wqw, Wvw, Wsw, Wh);
    proj_kernel<<<dim3((N_NODES + 63) / 64, 4), 256, 0, stream>>>(
        X, Wh, Wkb, Wqb, Wvb, Wsb, khp, q, vhp, out);

    hist_kernel<<<(N_EDGES + 255) / 256, 256, 0, stream>>>(dst, cnt);
    scanA_kernel<<<SCAN_NB, 1024, 0, stream>>>(cnt, partial, bsum);
    scanB_kernel<<<1, 1024, 0, stream>>>(partial, bsum, offs);
    scatter_kernel<<<(N_EDGES + 255) / 256, 256, 0, stream>>>(
        src, dst, ety, offs, cursor, pedge);

    attp_kernel<<<(N_EDGES + 15) / 16, 256, 0, stream>>>(
        khp, q, relw, pedge, attp);
    agg_kernel<<<AGG_NB, 256, 0, stream>>>(
        offs, (const unsigned*)pedge, attp, (const unsigned short*)vhp,
        alpha, out, bnpart);
    bnfin_kernel<<<25, 256, 0, stream>>>(bnpart, gamma, beta, bnsc, bnsh);
    apply_kernel<<<2048, 256, 0, stream>>>(out, bnsc, bnsh);
    rout_kernel<<<(20000 + 255) / 256, 256, 0, stream>>>(rfeat, Wrw, Wrb, out);
}

// Round 24
// 271.140 us; speedup vs baseline: 1.1227x; 1.1227x over previous
//
#include <hip/hip_runtime.h>
#include <hip/hip_bf16.h>
#include <math.h>

#define N_NODES 50000
#define N_EDGES 800000
#define BN_EPS  1e-5f
#define SCAN_NB 49     // ceil(50000/1024)
#define AGG_NB  2048   // agg grid blocks

typedef float floatx2 __attribute__((ext_vector_type(2)));
typedef _Float16 half2_t __attribute__((ext_vector_type(2)));

#if defined(__has_builtin) && __has_builtin(__builtin_amdgcn_fdot2)
#define FDOT2(a, b, c) __builtin_amdgcn_fdot2((a), (b), (c), false)
#else
#define FDOT2(a, b, c) ((c) + (float)(a).x * (float)(b).x + (float)(a).y * (float)(b).y)
#endif

union h2u { half2_t h; unsigned u; };

// ---- workspace layout (float-element offsets) ----
#define OFS_RELW   0                    // 200*128 padded relw
#define OFS_KH     25600                // 50000*32 uints (fp8 rows, 128B)
#define OFS_Q      1625600              // 50000*128 padded q
#define OFS_VH     8025600              // 50000*32 uints
#define OFS_ATTP   9625600
#define OFS_BNPART 10425600             // 200 * AGG_NB
#define OFS_BNSC   10835200
#define OFS_BNSH   10835328
#define OFS_CNT    10835456
#define OFS_PART   10885632
#define OFS_BSUM   10935808
#define OFS_OFFS   10935872
#define OFS_CURS   10986048
#define OFS_PEDGE  11036224             // 800000 x uint64: src|ety<<17|dst<<32
#define OFS_WT     12636224             // 4*50*104 packed half2 W
#define WS_ELEMS   12657024

// fused prep: zero cnt+cursor (blocks 0..391), relw (392..491, 200*128),
// wth pack (492..572, 4*50*104). Zeroing runs before hist (stream order).
__global__ __launch_bounds__(256) void prep_kernel(
    const float* __restrict__ wcomp, const float* __restrict__ ratt,
    const float* __restrict__ Wk, const float* __restrict__ Wq,
    const float* __restrict__ Wv, const float* __restrict__ Ws,
    float* __restrict__ relw, unsigned* __restrict__ Wth,
    int* __restrict__ cnt, int* __restrict__ cursor)
{
    const int b = blockIdx.x;
    const int tid = threadIdx.x;
    if (b < 392) {
        int i = b * 256 + tid;
        if (i < 50176) { cnt[i] = 0; cursor[i] = 0; }
    } else if (b < 492) {
        int o = (b - 392) * 256 + tid;
        if (o < 200 * 128) {
            int r = o / 128, c = o % 128;
            float acc = 0.f;
            if (c < 100) {
                #pragma unroll 10
                for (int k = 0; k < 50; ++k)
                    acc += wcomp[r * 50 + k] * ratt[k * 100 + c];
            }
            relw[o] = acc;
        }
    } else {
        int o = (b - 492) * 256 + tid;
        if (o < 4 * 50 * 104) {
            int m = o / 5200, rem = o % 5200, d2 = rem / 104, c = rem % 104;
            const float* W = (m == 0) ? Wk : (m == 1) ? Wq : (m == 2) ? Wv : Ws;
            float a = (c < 100) ? W[c * 100 + 2 * d2]     : 0.f;
            float bb = (c < 100) ? W[c * 100 + 2 * d2 + 1] : 0.f;
            h2u cv; cv.h = half2_t{(_Float16)a, (_Float16)bb};
            Wth[o] = cv.u;
        }
    }
}

// fused projections: proven fdot2 config (512 thr, 4x4 tile, 64-node tile,
// half2 LDS, XOR swizzle). k,v -> fp8 (32-word rows, pad 0); q -> fp32
// 128-col rows (pad 0); s -> fp32 100-col rows.
__global__ __launch_bounds__(512) void proj_kernel(
    const float* __restrict__ X, const unsigned* __restrict__ Wth,
    const float* __restrict__ bk, const float* __restrict__ bq,
    const float* __restrict__ bv, const float* __restrict__ bs,
    unsigned* __restrict__ khp, float* __restrict__ qo,
    unsigned* __restrict__ vhp, float* __restrict__ so)
{
    __shared__ unsigned Xth[50][68];    // 13.6 KB
    __shared__ unsigned Wlh[50][104];   // 20.8 KB
    const int tid = threadIdx.x;
    const int nb  = blockIdx.x * 64;
    const int m   = blockIdx.y;

    const float* bp = (m == 0) ? bk : (m == 1) ? bq : (m == 2) ? bv : bs;

    for (int idx = tid; idx < 1300; idx += 512) {
        int r = idx / 26, c4 = idx % 26;
        uint4 w = ((const uint4*)(Wth + m * 5200 + r * 104))[c4];
        *(uint4*)&Wlh[r][c4 * 4] = w;
    }
    for (int idx = tid; idx < 1600; idx += 512) {
        int n = idx / 25, d4 = idx % 25;
        int node = nb + n;
        float4 x = (node < N_NODES)
                   ? ((const float4*)(X + (size_t)node * 100))[d4]
                   : make_float4(0.f, 0.f, 0.f, 0.f);
        const int col = n ^ ((d4 & 7) << 2);
        h2u c0, c1;
        c0.h = half2_t{(_Float16)x.x, (_Float16)x.y};
        c1.h = half2_t{(_Float16)x.z, (_Float16)x.w};
        Xth[2 * d4][col]     = c0.u;
        Xth[2 * d4 + 1][col] = c1.u;
    }
    __syncthreads();

    const int nt  = tid & 15;        // node group: nodes 4nt..4nt+3
    const int ct  = tid >> 4;        // col group 0..31 (25 active compute)
    const bool act = (ct < 25);
    const int cts  = act ? ct : 24;

    float acc[4][4];
    #pragma unroll
    for (int i = 0; i < 4; ++i)
        #pragma unroll
        for (int j = 0; j < 4; ++j) acc[i][j] = 0.f;

    #pragma unroll 5
    for (int d2 = 0; d2 < 50; ++d2) {
        const int key = ((d2 >> 1) & 7) << 2;
        const uint4 xv = *(const uint4*)&Xth[d2][(4 * nt) ^ key];
        const uint4 wv = *(const uint4*)&Wlh[d2][4 * cts];
        h2u x0, x1, x2, x3, w0, w1, w2, w3;
        x0.u = xv.x; x1.u = xv.y; x2.u = xv.z; x3.u = xv.w;
        w0.u = wv.x; w1.u = wv.y; w2.u = wv.z; w3.u = wv.w;
        acc[0][0] = FDOT2(x0.h, w0.h, acc[0][0]);
        acc[0][1] = FDOT2(x0.h, w1.h, acc[0][1]);
        acc[0][2] = FDOT2(x0.h, w2.h, acc[0][2]);
        acc[0][3] = FDOT2(x0.h, w3.h, acc[0][3]);
        acc[1][0] = FDOT2(x1.h, w0.h, acc[1][0]);
        acc[1][1] = FDOT2(x1.h, w1.h, acc[1][1]);
        acc[1][2] = FDOT2(x1.h, w2.h, acc[1][2]);
        acc[1][3] = FDOT2(x1.h, w3.h, acc[1][3]);
        acc[2][0] = FDOT2(x2.h, w0.h, acc[2][0]);
        acc[2][1] = FDOT2(x2.h, w1.h, acc[2][1]);
        acc[2][2] = FDOT2(x2.h, w2.h, acc[2][2]);
        acc[2][3] = FDOT2(x2.h, w3.h, acc[2][3]);
        acc[3][0] = FDOT2(x3.h, w0.h, acc[3][0]);
        acc[3][1] = FDOT2(x3.h, w1.h, acc[3][1]);
        acc[3][2] = FDOT2(x3.h, w2.h, acc[3][2]);
        acc[3][3] = FDOT2(x3.h, w3.h, acc[3][3]);
    }

    const float4 bb = act ? *(const float4*)(bp + ct * 4)
                          : make_float4(0.f, 0.f, 0.f, 0.f);
    if (m == 0 || m == 2) {
        unsigned* oph = (m == 0) ? khp : vhp;
        #pragma unroll
        for (int i = 0; i < 4; ++i) {
            const int node = nb + nt * 4 + i;
            if (node < N_NODES) {
                unsigned wdo = 0u;
                if (act) {
                    int wd = 0;
                    wd = __builtin_amdgcn_cvt_pk_fp8_f32(
                        acc[i][0] + bb.x, acc[i][1] + bb.y, wd, false);
                    wd = __builtin_amdgcn_cvt_pk_fp8_f32(
                        acc[i][2] + bb.z, acc[i][3] + bb.w, wd, true);
                    wdo = (unsigned)wd;
                }
                oph[(size_t)node * 32 + ct] = wdo;
            }
        }
    } else if (m == 1) {
        #pragma unroll
        for (int i = 0; i < 4; ++i) {
            const int node = nb + nt * 4 + i;
            if (node < N_NODES) {
                float4 r = act ? make_float4(acc[i][0] + bb.x, acc[i][1] + bb.y,
                                             acc[i][2] + bb.z, acc[i][3] + bb.w)
                               : make_float4(0.f, 0.f, 0.f, 0.f);
                *(float4*)(qo + (size_t)node * 128 + ct * 4) = r;
            }
        }
    } else {
        if (act) {
            #pragma unroll
            for (int i = 0; i < 4; ++i) {
                const int node = nb + nt * 4 + i;
                if (node < N_NODES) {
                    float4 r = make_float4(acc[i][0] + bb.x, acc[i][1] + bb.y,
                                           acc[i][2] + bb.z, acc[i][3] + bb.w);
                    *(float4*)(so + (size_t)node * 100 + ct * 4) = r;
                }
            }
        }
    }
}

__global__ __launch_bounds__(256) void hist_kernel(
    const int* __restrict__ dst, int* __restrict__ cnt)
{
    int e = blockIdx.x * 256 + threadIdx.x;
    if (e < N_EDGES) atomicAdd(&cnt[dst[e]], 1);
}

__global__ __launch_bounds__(1024) void scanA_kernel(
    const int* __restrict__ cnt, int* __restrict__ partial, int* __restrict__ bsum)
{
    __shared__ int buf[1024];
    int tid = threadIdx.x;
    int i = blockIdx.x * 1024 + tid;
    int val = (i < N_NODES) ? cnt[i] : 0;
    buf[tid] = val;
    __syncthreads();
    for (int off = 1; off < 1024; off <<= 1) {
        int t = (tid >= off) ? buf[tid - off] : 0;
        __syncthreads();
        buf[tid] += t;
        __syncthreads();
    }
    int incl = buf[tid];
    if (i < N_NODES) partial[i] = incl - val;
    if (tid == 1023) bsum[blockIdx.x] = incl;
}

__global__ __launch_bounds__(1024) void scanB_kernel(
    const int* __restrict__ partial, const int* __restrict__ bsum,
    int* __restrict__ offs)
{
    __shared__ int bs[64];
    int tid = threadIdx.x;
    if (tid < SCAN_NB) bs[tid] = bsum[tid];
    __syncthreads();
    if (tid == 0) {
        int run = 0;
        for (int b = 0; b < SCAN_NB; ++b) { int t = bs[b]; bs[b] = run; run += t; }
    }
    __syncthreads();
    for (int i = tid; i < N_NODES; i += 1024) offs[i] = partial[i] + bs[i >> 10];
    if (tid == 0) offs[N_NODES] = N_EDGES;
}

// scatter ONE packed 8B word per edge: src | ety<<17 | dst<<32
__global__ __launch_bounds__(256) void scatter_kernel(
    const int* __restrict__ src, const int* __restrict__ dst,
    const int* __restrict__ ety, const int* __restrict__ offs,
    int* __restrict__ cursor, unsigned long long* __restrict__ pedge)
{
    int e = blockIdx.x * 256 + threadIdx.x;
    if (e >= N_EDGES) return;
    int d = dst[e];
    int p = atomicAdd(&cursor[d], 1);
    pedge[offs[d] + p] = (unsigned long long)(unsigned)src[e]
                       | ((unsigned long long)(unsigned)ety[e] << 17)
                       | ((unsigned long long)(unsigned)d << 32);
}

// attention logits: 16 lanes/edge on padded-128 rows; 4 edges/wave.
__global__ __launch_bounds__(256) void attp_kernel(
    const unsigned* __restrict__ khp, const float* __restrict__ q,
    const float* __restrict__ relw,
    const unsigned long long* __restrict__ pedge, float* __restrict__ attp)
{
    const int lane = threadIdx.x & 15;
    const int i = blockIdx.x * 16 + (threadIdx.x >> 4);
    if (i >= N_EDGES) return;
    const unsigned long long pw = pedge[i];
    const int s_ = (int)(pw & 0x1FFFFull);
    const int t_ = (int)((pw >> 17) & 0x7FFFull);
    const int d_ = (int)(pw >> 32);

    const unsigned* kr = khp + (size_t)s_ * 32;
    const float4*   qr = (const float4*)(q + (size_t)d_ * 128);
    const float4*   wr = (const float4*)(relw + t_ * 128);

    const unsigned kw0 = kr[lane];
    const unsigned kw1 = kr[lane + 16];
    const float4 qv0 = qr[lane];
    const float4 qv1 = qr[lane + 16];
    const float4 wv0 = wr[lane];
    const float4 wv1 = wr[lane + 16];

    const floatx2 ka = __builtin_amdgcn_cvt_pk_f32_fp8((int)kw0, false);
    const floatx2 kb = __builtin_amdgcn_cvt_pk_f32_fp8((int)kw0, true);
    const floatx2 kc = __builtin_amdgcn_cvt_pk_f32_fp8((int)kw1, false);
    const floatx2 kd = __builtin_amdgcn_cvt_pk_f32_fp8((int)kw1, true);

    float acc = ka[0] * wv0.x * qv0.x + ka[1] * wv0.y * qv0.y
              + kb[0] * wv0.z * qv0.z + kb[1] * wv0.w * qv0.w
              + kc[0] * wv1.x * qv1.x + kc[1] * wv1.y * qv1.y
              + kd[0] * wv1.z * qv1.z + kd[1] * wv1.w * qv1.w;

    #pragma unroll
    for (int off = 8; off > 0; off >>= 1) acc += __shfl_xor(acc, off, 16);
    if (lane == 0) attp[i] = acc;
}

// one wave per node: softmax (no max-shift: logits bounded, exp well-
// conditioned; identical up to rounding) + weighted-V aggregate (v fp8)
// + gated combine + BN partials. src read from low word of pedge.
__global__ __launch_bounds__(256) void agg_kernel(
    const int* __restrict__ offs, const unsigned* __restrict__ pedge32,
    const float* __restrict__ attp, const unsigned short* __restrict__ vhp,
    const float* __restrict__ alpha, float* __restrict__ out,
    float* __restrict__ bnpart)
{
    __shared__ float ls[100], lq[100];
    const int tid = threadIdx.x;
    if (tid < 100) { ls[tid] = 0.f; lq[tid] = 0.f; }
    __syncthreads();
    const int lane = tid & 63;
    const int gwave = blockIdx.x * 4 + (tid >> 6);
    const int nwaves = AGG_NB * 4;
    const float a = 1.f / (1.f + __expf(-alpha[0]));
    const float b = 1.f - a;
    const int cl = lane;             // lane owns columns 2cl, 2cl+1
    const bool act = (cl < 50);
    float sx = 0.f, sy = 0.f, qx = 0.f, qy = 0.f;

    for (int n = gwave; n < N_NODES; n += nwaves) {
        const int beg = offs[n], end = offs[n + 1];
        float ax = 0.f, ay = 0.f, wsum = 0.f;
        int i = beg;
        for (; i + 4 <= end; i += 4) {
            const int s0 = (int)(pedge32[2 * (i)]     & 0x1FFFFu);
            const int s1 = (int)(pedge32[2 * (i + 1)] & 0x1FFFFu);
            const int s2 = (int)(pedge32[2 * (i + 2)] & 0x1FFFFu);
            const int s3 = (int)(pedge32[2 * (i + 3)] & 0x1FFFFu);
            const float w0 = __expf(attp[i]),     w1 = __expf(attp[i + 1]);
            const float w2 = __expf(attp[i + 2]), w3 = __expf(attp[i + 3]);
            wsum += w0 + w1 + w2 + w3;
            if (act) {
                const unsigned short h0 = vhp[(size_t)s0 * 64 + cl];
                const unsigned short h1 = vhp[(size_t)s1 * 64 + cl];
                const unsigned short h2 = vhp[(size_t)s2 * 64 + cl];
                const unsigned short h3 = vhp[(size_t)s3 * 64 + cl];
                const floatx2 v0 = __builtin_amdgcn_cvt_pk_f32_fp8((int)h0, false);
                const floatx2 v1 = __builtin_amdgcn_cvt_pk_f32_fp8((int)h1, false);
                const floatx2 v2 = __builtin_amdgcn_cvt_pk_f32_fp8((int)h2, false);
                const floatx2 v3 = __builtin_amdgcn_cvt_pk_f32_fp8((int)h3, false);
                ax += w0 * v0[0] + w1 * v1[0] + w2 * v2[0] + w3 * v3[0];
                ay += w0 * v0[1] + w1 * v1[1] + w2 * v2[1] + w3 * v3[1];
            }
        }
        for (; i < end; ++i) {
            const int s0 = (int)(pedge32[2 * i] & 0x1FFFFu);
            const float w0 = __expf(attp[i]);
            wsum += w0;
            if (act) {
                const unsigned short h0 = vhp[(size_t)s0 * 64 + cl];
                const floatx2 v0 = __builtin_amdgcn_cvt_pk_f32_fp8((int)h0, false);
                ax += w0 * v0[0];
                ay += w0 * v0[1];
            }
        }
        const float inv = (wsum > 0.f) ? 1.f / wsum : 0.f;
        if (act) {
            float2* po = (float2*)(out + (size_t)n * 100);
            float2 cur = po[cl];
            float v0 = a * cur.x + b * ax * inv;
            float v1 = a * cur.y + b * ay * inv;
            po[cl] = make_float2(v0, v1);
            sx += v0; qx += v0 * v0;
            sy += v1; qy += v1 * v1;
        }
    }
    if (act) {
        atomicAdd(&ls[2 * cl], sx);     atomicAdd(&ls[2 * cl + 1], sy);
        atomicAdd(&lq[2 * cl], qx);     atomicAdd(&lq[2 * cl + 1], qy);
    }
    __syncthreads();
    if (tid < 100) {
        bnpart[(size_t)tid * AGG_NB + blockIdx.x]         = ls[tid];
        bnpart[(size_t)(tid + 100) * AGG_NB + blockIdx.x] = lq[tid];
    }
}

__global__ __launch_bounds__(256) void bnfin_kernel(
    const float* __restrict__ bnpart,
    const float* __restrict__ gamma, const float* __restrict__ beta,
    float* __restrict__ bnsc, float* __restrict__ bnsh)
{
    const int c = blockIdx.x * 4 + (threadIdx.x >> 6);
    const int lane = threadIdx.x & 63;
    if (c >= 100) return;
    float s = 0.f, q = 0.f;
    for (int b2 = lane; b2 < AGG_NB; b2 += 64) {
        s += bnpart[(size_t)c * AGG_NB + b2];
        q += bnpart[(size_t)(c + 100) * AGG_NB + b2];
    }
    #pragma unroll
    for (int off = 32; off > 0; off >>= 1) {
        s += __shfl_xor(s, off, 64);
        q += __shfl_xor(q, off, 64);
    }
    if (lane == 0) {
        const float inv_n = 1.f / (float)N_NODES;
        float mean = s * inv_n;
        float var = q * inv_n - mean * mean;
        float sc = gamma[c] * rsqrtf(var + BN_EPS);
        bnsc[c] = sc;
        bnsh[c] = beta[c] - mean * sc;
    }
}

// fused: BN-apply+tanh (blocks < 2048) and r_out GEMM (blocks >= 2048)
__global__ __launch_bounds__(256) void applyrout_kernel(
    float* __restrict__ out, const float* __restrict__ bnsc,
    const float* __restrict__ bnsh,
    const float* __restrict__ rf, const float* __restrict__ Wr,
    const float* __restrict__ br)
{
    if (blockIdx.x < 2048) {
        const int total4 = N_NODES * 25;
        for (int idx = blockIdx.x * 256 + threadIdx.x; idx < total4; idx += 2048 * 256) {
            float4* p = ((float4*)out) + idx;
            const int c = (idx % 25) * 4;
            float4 t = *p;
            t.x = tanhf(t.x * bnsc[c]     + bnsh[c]);
            t.y = tanhf(t.y * bnsc[c + 1] + bnsh[c + 1]);
            t.z = tanhf(t.z * bnsc[c + 2] + bnsh[c + 2]);
            t.w = tanhf(t.w * bnsc[c + 3] + bnsh[c + 3]);
            *p = t;
        }
    } else {
        int o = (blockIdx.x - 2048) * 256 + threadIdx.x;
        if (o < 200 * 100) {
            int r = o / 100, c = o % 100;
            float acc = br[c];
            #pragma unroll 10
            for (int d = 0; d < 100; ++d) acc += rf[r * 100 + d] * Wr[c * 100 + d];
            out[N_NODES * 100 + o] = acc;
        }
    }
}

extern "C" void kernel_launch(void* const* d_in, const int* in_sizes, int n_in,
                              void* d_out, int out_size, void* d_ws, size_t ws_size,
                              hipStream_t stream) {
    const float* X     = (const float*)d_in[0];
    const float* rfeat = (const float*)d_in[1];
    const int*   src   = (const int*)d_in[2];
    const int*   dst   = (const int*)d_in[3];
    const int*   ety   = (const int*)d_in[4];
    const float* Wsw   = (const float*)d_in[6];
    const float* Wsb   = (const float*)d_in[7];
    const float* Wkw   = (const float*)d_in[8];
    const float* Wkb   = (const float*)d_in[9];
    const float* Wqw   = (const float*)d_in[10];
    const float* Wqb   = (const float*)d_in[11];
    const float* Wvw   = (const float*)d_in[12];
    const float* Wvb   = (const float*)d_in[13];
    const float* Wrw   = (const float*)d_in[14];
    const float* Wrb   = (const float*)d_in[15];
    const float* ratt  = (const float*)d_in[16];
    const float* wcomp = (const float*)d_in[17];
    const float* alpha = (const float*)d_in[18];
    const float* gamma = (const float*)d_in[20];
    const float* beta  = (const float*)d_in[21];

    float* out = (float*)d_out;
    float* ws  = (float*)d_ws;
    if (ws_size < (size_t)WS_ELEMS * sizeof(float)) return;

    float* relw          = ws + OFS_RELW;
    unsigned* khp        = (unsigned*)(ws + OFS_KH);
    float* q             = ws + OFS_Q;
    unsigned* vhp        = (unsigned*)(ws + OFS_VH);
    float* attp          = ws + OFS_ATTP;
    float* bnpart        = ws + OFS_BNPART;
    float* bnsc          = ws + OFS_BNSC;
    float* bnsh          = ws + OFS_BNSH;
    unsigned* Wth        = (unsigned*)(ws + OFS_WT);
    int* cnt             = (int*)(ws + OFS_CNT);
    int* partial         = (int*)(ws + OFS_PART);
    int* bsum            = (int*)(ws + OFS_BSUM);
    int* offs            = (int*)(ws + OFS_OFFS);
    int* cursor          = (int*)(ws + OFS_CURS);
    unsigned long long* pedge = (unsigned long long*)(ws + OFS_PEDGE);

    prep_kernel<<<392 + 100 + 82, 256, 0, stream>>>(
        wcomp, ratt, Wkw, Wqw, Wvw, Wsw, relw, Wth, cnt, cursor);
    proj_kernel<<<dim3((N_NODES + 63) / 64, 4), 512, 0, stream>>>(
        X, Wth, Wkb, Wqb, Wvb, Wsb, khp, q, vhp, out);

    hist_kernel<<<(N_EDGES + 255) / 256, 256, 0, stream>>>(dst, cnt);
    scanA_kernel<<<SCAN_NB, 1024, 0, stream>>>(cnt, partial, bsum);
    scanB_kernel<<<1, 1024, 0, stream>>>(partial, bsum, offs);
    scatter_kernel<<<(N_EDGES + 255) / 256, 256, 0, stream>>>(
        src, dst, ety, offs, cursor, pedge);

    attp_kernel<<<(N_EDGES + 15) / 16, 256, 0, stream>>>(
        khp, q, relw, pedge, attp);
    agg_kernel<<<AGG_NB, 256, 0, stream>>>(
        offs, (const unsigned*)pedge, attp, (const unsigned short*)vhp,
        alpha, out, bnpart);
    bnfin_kernel<<<25, 256, 0, stream>>>(bnpart, gamma, beta, bnsc, bnsh);
    applyrout_kernel<<<2048 + (20000 + 255) / 256, 256, 0, stream>>>(
        out, bnsc, bnsh, rfeat, Wrw, Wrb);
}

// Round 25
// 233.361 us; speedup vs baseline: 1.3044x; 1.1619x over previous
//
#include <hip/hip_runtime.h>
#include <hip/hip_bf16.h>
#include <math.h>

#define N_NODES 50000
#define N_EDGES 800000
#define BN_EPS  1e-5f
#define SCAN_NB 49     // ceil(50000/1024)
#define AGG_NB  2048   // agg grid blocks

typedef float floatx2 __attribute__((ext_vector_type(2)));
typedef _Float16 half2_t __attribute__((ext_vector_type(2)));

#if defined(__has_builtin) && __has_builtin(__builtin_amdgcn_fdot2)
#define FDOT2(a, b, c) __builtin_amdgcn_fdot2((a), (b), (c), false)
#else
#define FDOT2(a, b, c) ((c) + (float)(a).x * (float)(b).x + (float)(a).y * (float)(b).y)
#endif

union h2u { half2_t h; unsigned u; };

// ---- workspace layout (float-element offsets) ----
#define OFS_RELW   0                    // 200*128 padded relw
#define OFS_KH     25600                // 50000*32 uints (fp8 rows, 128B)
#define OFS_Q      1625600              // 50000*128 padded q
#define OFS_VH     8025600              // 50000*32 uints
#define OFS_ATTP   9625600
#define OFS_BNPART 10425600             // 200 * AGG_NB
#define OFS_BNSC   10835200
#define OFS_BNSH   10835328
#define OFS_CNT    10835456
#define OFS_PART   10885632
#define OFS_BSUM   10935808
#define OFS_OFFS   10935872
#define OFS_RANK   10986048             // 800000 ints: edge rank within dst
#define OFS_PEDGE  11786048             // 800000 x uint64: src|ety<<17|dst<<32
#define OFS_WT     13386048             // 4*50*104 packed half2 W
#define WS_ELEMS   13406848

// fused prep: zero cnt (blocks 0..195), relw (196..295), wth pack (296..377)
__global__ __launch_bounds__(256) void prep_kernel(
    const float* __restrict__ wcomp, const float* __restrict__ ratt,
    const float* __restrict__ Wk, const float* __restrict__ Wq,
    const float* __restrict__ Wv, const float* __restrict__ Ws,
    float* __restrict__ relw, unsigned* __restrict__ Wth,
    int* __restrict__ cnt)
{
    const int b = blockIdx.x;
    const int tid = threadIdx.x;
    if (b < 196) {
        int i = b * 256 + tid;
        if (i < 50176) cnt[i] = 0;
    } else if (b < 296) {
        int o = (b - 196) * 256 + tid;
        if (o < 200 * 128) {
            int r = o / 128, c = o % 128;
            float acc = 0.f;
            if (c < 100) {
                #pragma unroll 10
                for (int k = 0; k < 50; ++k)
                    acc += wcomp[r * 50 + k] * ratt[k * 100 + c];
            }
            relw[o] = acc;
        }
    } else {
        int o = (b - 296) * 256 + tid;
        if (o < 4 * 50 * 104) {
            int m = o / 5200, rem = o % 5200, d2 = rem / 104, c = rem % 104;
            const float* W = (m == 0) ? Wk : (m == 1) ? Wq : (m == 2) ? Wv : Ws;
            float a = (c < 100) ? W[c * 100 + 2 * d2]     : 0.f;
            float bb = (c < 100) ? W[c * 100 + 2 * d2 + 1] : 0.f;
            h2u cv; cv.h = half2_t{(_Float16)a, (_Float16)bb};
            Wth[o] = cv.u;
        }
    }
}

// fused projections: proven fdot2 config (512 thr, 4x4 tile, 64-node tile,
// half2 LDS, XOR swizzle). k,v -> fp8 (32-word rows, pad 0); q -> fp32
// 128-col rows (pad 0); s -> fp32 100-col rows.
__global__ __launch_bounds__(512) void proj_kernel(
    const float* __restrict__ X, const unsigned* __restrict__ Wth,
    const float* __restrict__ bk, const float* __restrict__ bq,
    const float* __restrict__ bv, const float* __restrict__ bs,
    unsigned* __restrict__ khp, float* __restrict__ qo,
    unsigned* __restrict__ vhp, float* __restrict__ so)
{
    __shared__ unsigned Xth[50][68];    // 13.6 KB
    __shared__ unsigned Wlh[50][104];   // 20.8 KB
    const int tid = threadIdx.x;
    const int nb  = blockIdx.x * 64;
    const int m   = blockIdx.y;

    const float* bp = (m == 0) ? bk : (m == 1) ? bq : (m == 2) ? bv : bs;

    for (int idx = tid; idx < 1300; idx += 512) {
        int r = idx / 26, c4 = idx % 26;
        uint4 w = ((const uint4*)(Wth + m * 5200 + r * 104))[c4];
        *(uint4*)&Wlh[r][c4 * 4] = w;
    }
    for (int idx = tid; idx < 1600; idx += 512) {
        int n = idx / 25, d4 = idx % 25;
        int node = nb + n;
        float4 x = (node < N_NODES)
                   ? ((const float4*)(X + (size_t)node * 100))[d4]
                   : make_float4(0.f, 0.f, 0.f, 0.f);
        const int col = n ^ ((d4 & 7) << 2);
        h2u c0, c1;
        c0.h = half2_t{(_Float16)x.x, (_Float16)x.y};
        c1.h = half2_t{(_Float16)x.z, (_Float16)x.w};
        Xth[2 * d4][col]     = c0.u;
        Xth[2 * d4 + 1][col] = c1.u;
    }
    __syncthreads();

    const int nt  = tid & 15;        // node group: nodes 4nt..4nt+3
    const int ct  = tid >> 4;        // col group 0..31 (25 active compute)
    const bool act = (ct < 25);
    const int cts  = act ? ct : 24;

    float acc[4][4];
    #pragma unroll
    for (int i = 0; i < 4; ++i)
        #pragma unroll
        for (int j = 0; j < 4; ++j) acc[i][j] = 0.f;

    #pragma unroll 5
    for (int d2 = 0; d2 < 50; ++d2) {
        const int key = ((d2 >> 1) & 7) << 2;
        const uint4 xv = *(const uint4*)&Xth[d2][(4 * nt) ^ key];
        const uint4 wv = *(const uint4*)&Wlh[d2][4 * cts];
        h2u x0, x1, x2, x3, w0, w1, w2, w3;
        x0.u = xv.x; x1.u = xv.y; x2.u = xv.z; x3.u = xv.w;
        w0.u = wv.x; w1.u = wv.y; w2.u = wv.z; w3.u = wv.w;
        acc[0][0] = FDOT2(x0.h, w0.h, acc[0][0]);
        acc[0][1] = FDOT2(x0.h, w1.h, acc[0][1]);
        acc[0][2] = FDOT2(x0.h, w2.h, acc[0][2]);
        acc[0][3] = FDOT2(x0.h, w3.h, acc[0][3]);
        acc[1][0] = FDOT2(x1.h, w0.h, acc[1][0]);
        acc[1][1] = FDOT2(x1.h, w1.h, acc[1][1]);
        acc[1][2] = FDOT2(x1.h, w2.h, acc[1][2]);
        acc[1][3] = FDOT2(x1.h, w3.h, acc[1][3]);
        acc[2][0] = FDOT2(x2.h, w0.h, acc[2][0]);
        acc[2][1] = FDOT2(x2.h, w1.h, acc[2][1]);
        acc[2][2] = FDOT2(x2.h, w2.h, acc[2][2]);
        acc[2][3] = FDOT2(x2.h, w3.h, acc[2][3]);
        acc[3][0] = FDOT2(x3.h, w0.h, acc[3][0]);
        acc[3][1] = FDOT2(x3.h, w1.h, acc[3][1]);
        acc[3][2] = FDOT2(x3.h, w2.h, acc[3][2]);
        acc[3][3] = FDOT2(x3.h, w3.h, acc[3][3]);
    }

    const float4 bb = act ? *(const float4*)(bp + ct * 4)
                          : make_float4(0.f, 0.f, 0.f, 0.f);
    if (m == 0 || m == 2) {
        unsigned* oph = (m == 0) ? khp : vhp;
        #pragma unroll
        for (int i = 0; i < 4; ++i) {
            const int node = nb + nt * 4 + i;
            if (node < N_NODES) {
                unsigned wdo = 0u;
                if (act) {
                    int wd = 0;
                    wd = __builtin_amdgcn_cvt_pk_fp8_f32(
                        acc[i][0] + bb.x, acc[i][1] + bb.y, wd, false);
                    wd = __builtin_amdgcn_cvt_pk_fp8_f32(
                        acc[i][2] + bb.z, acc[i][3] + bb.w, wd, true);
                    wdo = (unsigned)wd;
                }
                oph[(size_t)node * 32 + ct] = wdo;
            }
        }
    } else if (m == 1) {
        #pragma unroll
        for (int i = 0; i < 4; ++i) {
            const int node = nb + nt * 4 + i;
            if (node < N_NODES) {
                float4 r = act ? make_float4(acc[i][0] + bb.x, acc[i][1] + bb.y,
                                             acc[i][2] + bb.z, acc[i][3] + bb.w)
                               : make_float4(0.f, 0.f, 0.f, 0.f);
                *(float4*)(qo + (size_t)node * 128 + ct * 4) = r;
            }
        }
    } else {
        if (act) {
            #pragma unroll
            for (int i = 0; i < 4; ++i) {
                const int node = nb + nt * 4 + i;
                if (node < N_NODES) {
                    float4 r = make_float4(acc[i][0] + bb.x, acc[i][1] + bb.y,
                                           acc[i][2] + bb.z, acc[i][3] + bb.w);
                    *(float4*)(so + (size_t)node * 100 + ct * 4) = r;
                }
            }
        }
    }
}

// histogram + per-edge rank (atomicAdd return value), rank write coalesced
__global__ __launch_bounds__(256) void hist_kernel(
    const int* __restrict__ dst, int* __restrict__ cnt, int* __restrict__ rank)
{
    int e = blockIdx.x * 256 + threadIdx.x;
    if (e < N_EDGES) rank[e] = atomicAdd(&cnt[dst[e]], 1);
}

__global__ __launch_bounds__(1024) void scanA_kernel(
    const int* __restrict__ cnt, int* __restrict__ partial, int* __restrict__ bsum)
{
    __shared__ int buf[1024];
    int tid = threadIdx.x;
    int i = blockIdx.x * 1024 + tid;
    int val = (i < N_NODES) ? cnt[i] : 0;
    buf[tid] = val;
    __syncthreads();
    for (int off = 1; off < 1024; off <<= 1) {
        int t = (tid >= off) ? buf[tid - off] : 0;
        __syncthreads();
        buf[tid] += t;
        __syncthreads();
    }
    int incl = buf[tid];
    if (i < N_NODES) partial[i] = incl - val;
    if (tid == 1023) bsum[blockIdx.x] = incl;
}

__global__ __launch_bounds__(1024) void scanB_kernel(
    const int* __restrict__ partial, const int* __restrict__ bsum,
    int* __restrict__ offs)
{
    __shared__ int bs[64];
    int tid = threadIdx.x;
    if (tid < SCAN_NB) bs[tid] = bsum[tid];
    __syncthreads();
    if (tid == 0) {
        int run = 0;
        for (int b = 0; b < SCAN_NB; ++b) { int t = bs[b]; bs[b] = run; run += t; }
    }
    __syncthreads();
    for (int i = tid; i < N_NODES; i += 1024) offs[i] = partial[i] + bs[i >> 10];
    if (tid == 0) offs[N_NODES] = N_EDGES;
}

// scatter: NO atomics -- pos = offs[dst] + rank (rank from hist). One
// packed 8B random write per edge; dst/rank/src/ety reads all coalesced.
__global__ __launch_bounds__(256) void scatter_kernel(
    const int* __restrict__ src, const int* __restrict__ dst,
    const int* __restrict__ ety, const int* __restrict__ offs,
    const int* __restrict__ rank, unsigned long long* __restrict__ pedge)
{
    int e = blockIdx.x * 256 + threadIdx.x;
    if (e >= N_EDGES) return;
    int d = dst[e];
    pedge[offs[d] + rank[e]] = (unsigned long long)(unsigned)src[e]
                             | ((unsigned long long)(unsigned)ety[e] << 17)
                             | ((unsigned long long)(unsigned)d << 32);
}

// attention weights: 16 lanes/edge on padded-128 rows; 4 edges/wave.
// Stores exp(logit) directly (no max-shift; logits bounded) so agg's
// inner loop needs no transcendental ops.
__global__ __launch_bounds__(256) void attp_kernel(
    const unsigned* __restrict__ khp, const float* __restrict__ q,
    const float* __restrict__ relw,
    const unsigned long long* __restrict__ pedge, float* __restrict__ attp)
{
    const int lane = threadIdx.x & 15;
    const int i = blockIdx.x * 16 + (threadIdx.x >> 4);
    if (i >= N_EDGES) return;
    const unsigned long long pw = pedge[i];
    const int s_ = (int)(pw & 0x1FFFFull);
    const int t_ = (int)((pw >> 17) & 0x7FFFull);
    const int d_ = (int)(pw >> 32);

    const unsigned* kr = khp + (size_t)s_ * 32;
    const float4*   qr = (const float4*)(q + (size_t)d_ * 128);
    const float4*   wr = (const float4*)(relw + t_ * 128);

    const unsigned kw0 = kr[lane];
    const unsigned kw1 = kr[lane + 16];
    const float4 qv0 = qr[lane];
    const float4 qv1 = qr[lane + 16];
    const float4 wv0 = wr[lane];
    const float4 wv1 = wr[lane + 16];

    const floatx2 ka = __builtin_amdgcn_cvt_pk_f32_fp8((int)kw0, false);
    const floatx2 kb = __builtin_amdgcn_cvt_pk_f32_fp8((int)kw0, true);
    const floatx2 kc = __builtin_amdgcn_cvt_pk_f32_fp8((int)kw1, false);
    const floatx2 kd = __builtin_amdgcn_cvt_pk_f32_fp8((int)kw1, true);

    float acc = ka[0] * wv0.x * qv0.x + ka[1] * wv0.y * qv0.y
              + kb[0] * wv0.z * qv0.z + kb[1] * wv0.w * qv0.w
              + kc[0] * wv1.x * qv1.x + kc[1] * wv1.y * qv1.y
              + kd[0] * wv1.z * qv1.z + kd[1] * wv1.w * qv1.w;

    #pragma unroll
    for (int off = 8; off > 0; off >>= 1) acc += __shfl_xor(acc, off, 16);
    if (lane == 0) attp[i] = __expf(acc);
}

// one wave per node: weighted-V aggregate (weights precomputed in attp,
// v fp8) + gated combine + BN partials. src read from low word of pedge.
__global__ __launch_bounds__(256) void agg_kernel(
    const int* __restrict__ offs, const unsigned* __restrict__ pedge32,
    const float* __restrict__ attp, const unsigned short* __restrict__ vhp,
    const float* __restrict__ alpha, float* __restrict__ out,
    float* __restrict__ bnpart)
{
    __shared__ float ls[100], lq[100];
    const int tid = threadIdx.x;
    if (tid < 100) { ls[tid] = 0.f; lq[tid] = 0.f; }
    __syncthreads();
    const int lane = tid & 63;
    const int gwave = blockIdx.x * 4 + (tid >> 6);
    const int nwaves = AGG_NB * 4;
    const float a = 1.f / (1.f + __expf(-alpha[0]));
    const float b = 1.f - a;
    const int cl = lane;             // lane owns columns 2cl, 2cl+1
    const bool act = (cl < 50);
    float sx = 0.f, sy = 0.f, qx = 0.f, qy = 0.f;

    for (int n = gwave; n < N_NODES; n += nwaves) {
        const int beg = offs[n], end = offs[n + 1];
        float ax = 0.f, ay = 0.f, wsum = 0.f;
        int i = beg;
        for (; i + 4 <= end; i += 4) {
            const int s0 = (int)(pedge32[2 * (i)]     & 0x1FFFFu);
            const int s1 = (int)(pedge32[2 * (i + 1)] & 0x1FFFFu);
            const int s2 = (int)(pedge32[2 * (i + 2)] & 0x1FFFFu);
            const int s3 = (int)(pedge32[2 * (i + 3)] & 0x1FFFFu);
            const float w0 = attp[i],     w1 = attp[i + 1];
            const float w2 = attp[i + 2], w3 = attp[i + 3];
            wsum += w0 + w1 + w2 + w3;
            if (act) {
                const unsigned short h0 = vhp[(size_t)s0 * 64 + cl];
                const unsigned short h1 = vhp[(size_t)s1 * 64 + cl];
                const unsigned short h2 = vhp[(size_t)s2 * 64 + cl];
                const unsigned short h3 = vhp[(size_t)s3 * 64 + cl];
                const floatx2 v0 = __builtin_amdgcn_cvt_pk_f32_fp8((int)h0, false);
                const floatx2 v1 = __builtin_amdgcn_cvt_pk_f32_fp8((int)h1, false);
                const floatx2 v2 = __builtin_amdgcn_cvt_pk_f32_fp8((int)h2, false);
                const floatx2 v3 = __builtin_amdgcn_cvt_pk_f32_fp8((int)h3, false);
                ax += w0 * v0[0] + w1 * v1[0] + w2 * v2[0] + w3 * v3[0];
                ay += w0 * v0[1] + w1 * v1[1] + w2 * v2[1] + w3 * v3[1];
            }
        }
        for (; i < end; ++i) {
            const int s0 = (int)(pedge32[2 * i] & 0x1FFFFu);
            const float w0 = attp[i];
            wsum += w0;
            if (act) {
                const unsigned short h0 = vhp[(size_t)s0 * 64 + cl];
                const floatx2 v0 = __builtin_amdgcn_cvt_pk_f32_fp8((int)h0, false);
                ax += w0 * v0[0];
                ay += w0 * v0[1];
            }
        }
        const float inv = (wsum > 0.f) ? 1.f / wsum : 0.f;
        if (act) {
            float2* po = (float2*)(out + (size_t)n * 100);
            float2 cur = po[cl];
            float v0 = a * cur.x + b * ax * inv;
            float v1 = a * cur.y + b * ay * inv;
            po[cl] = make_float2(v0, v1);
            sx += v0; qx += v0 * v0;
            sy += v1; qy += v1 * v1;
        }
    }
    if (act) {
        atomicAdd(&ls[2 * cl], sx);     atomicAdd(&ls[2 * cl + 1], sy);
        atomicAdd(&lq[2 * cl], qx);     atomicAdd(&lq[2 * cl + 1], qy);
    }
    __syncthreads();
    if (tid < 100) {
        bnpart[(size_t)tid * AGG_NB + blockIdx.x]         = ls[tid];
        bnpart[(size_t)(tid + 100) * AGG_NB + blockIdx.x] = lq[tid];
    }
}

__global__ __launch_bounds__(256) void bnfin_kernel(
    const float* __restrict__ bnpart,
    const float* __restrict__ gamma, const float* __restrict__ beta,
    float* __restrict__ bnsc, float* __restrict__ bnsh)
{
    const int c = blockIdx.x * 4 + (threadIdx.x >> 6);
    const int lane = threadIdx.x & 63;
    if (c >= 100) return;
    float s = 0.f, q = 0.f;
    for (int b2 = lane; b2 < AGG_NB; b2 += 64) {
        s += bnpart[(size_t)c * AGG_NB + b2];
        q += bnpart[(size_t)(c + 100) * AGG_NB + b2];
    }
    #pragma unroll
    for (int off = 32; off > 0; off >>= 1) {
        s += __shfl_xor(s, off, 64);
        q += __shfl_xor(q, off, 64);
    }
    if (lane == 0) {
        const float inv_n = 1.f / (float)N_NODES;
        float mean = s * inv_n;
        float var = q * inv_n - mean * mean;
        float sc = gamma[c] * rsqrtf(var + BN_EPS);
        bnsc[c] = sc;
        bnsh[c] = beta[c] - mean * sc;
    }
}

// fused: BN-apply+tanh (blocks < 2048) and r_out GEMM (blocks >= 2048)
__global__ __launch_bounds__(256) void applyrout_kernel(
    float* __restrict__ out, const float* __restrict__ bnsc,
    const float* __restrict__ bnsh,
    const float* __restrict__ rf, const float* __restrict__ Wr,
    const float* __restrict__ br)
{
    if (blockIdx.x < 2048) {
        const int total4 = N_NODES * 25;
        for (int idx = blockIdx.x * 256 + threadIdx.x; idx < total4; idx += 2048 * 256) {
            float4* p = ((float4*)out) + idx;
            const int c = (idx % 25) * 4;
            float4 t = *p;
            t.x = tanhf(t.x * bnsc[c]     + bnsh[c]);
            t.y = tanhf(t.y * bnsc[c + 1] + bnsh[c + 1]);
            t.z = tanhf(t.z * bnsc[c + 2] + bnsh[c + 2]);
            t.w = tanhf(t.w * bnsc[c + 3] + bnsh[c + 3]);
            *p = t;
        }
    } else {
        int o = (blockIdx.x - 2048) * 256 + threadIdx.x;
        if (o < 200 * 100) {
            int r = o / 100, c = o % 100;
            float acc = br[c];
            #pragma unroll 10
            for (int d = 0; d < 100; ++d) acc += rf[r * 100 + d] * Wr[c * 100 + d];
            out[N_NODES * 100 + o] = acc;
        }
    }
}

extern "C" void kernel_launch(void* const* d_in, const int* in_sizes, int n_in,
                              void* d_out, int out_size, void* d_ws, size_t ws_size,
                              hipStream_t stream) {
    const float* X     = (const float*)d_in[0];
    const float* rfeat = (const float*)d_in[1];
    const int*   src   = (const int*)d_in[2];
    const int*   dst   = (const int*)d_in[3];
    const int*   ety   = (const int*)d_in[4];
    const float* Wsw   = (const float*)d_in[6];
    const float* Wsb   = (const float*)d_in[7];
    const float* Wkw   = (const float*)d_in[8];
    const float* Wkb   = (const float*)d_in[9];
    const float* Wqw   = (const float*)d_in[10];
    const float* Wqb   = (const float*)d_in[11];
    const float* Wvw   = (const float*)d_in[12];
    const float* Wvb   = (const float*)d_in[13];
    const float* Wrw   = (const float*)d_in[14];
    const float* Wrb   = (const float*)d_in[15];
    const float* ratt  = (const float*)d_in[16];
    const float* wcomp = (const float*)d_in[17];
    const float* alpha = (const float*)d_in[18];
    const float* gamma = (const float*)d_in[20];
    const float* beta  = (const float*)d_in[21];

    float* out = (float*)d_out;
    float* ws  = (float*)d_ws;
    if (ws_size < (size_t)WS_ELEMS * sizeof(float)) return;

    float* relw          = ws + OFS_RELW;
    unsigned* khp        = (unsigned*)(ws + OFS_KH);
    float* q             = ws + OFS_Q;
    unsigned* vhp        = (unsigned*)(ws + OFS_VH);
    float* attp          = ws + OFS_ATTP;
    float* bnpart        = ws + OFS_BNPART;
    float* bnsc          = ws + OFS_BNSC;
    float* bnsh          = ws + OFS_BNSH;
    unsigned* Wth        = (unsigned*)(ws + OFS_WT);
    int* cnt             = (int*)(ws + OFS_CNT);
    int* partial         = (int*)(ws + OFS_PART);
    int* bsum            = (int*)(ws + OFS_BSUM);
    int* offs            = (int*)(ws + OFS_OFFS);
    int* rank            = (int*)(ws + OFS_RANK);
    unsigned long long* pedge = (unsigned long long*)(ws + OFS_PEDGE);

    prep_kernel<<<196 + 100 + 82, 256, 0, stream>>>(
        wcomp, ratt, Wkw, Wqw, Wvw, Wsw, relw, Wth, cnt);
    proj_kernel<<<dim3((N_NODES + 63) / 64, 4), 512, 0, stream>>>(
        X, Wth, Wkb, Wqb, Wvb, Wsb, khp, q, vhp, out);

    hist_kernel<<<(N_EDGES + 255) / 256, 256, 0, stream>>>(dst, cnt, rank);
    scanA_kernel<<<SCAN_NB, 1024, 0, stream>>>(cnt, partial, bsum);
    scanB_kernel<<<1, 1024, 0, stream>>>(partial, bsum, offs);
    scatter_kernel<<<(N_EDGES + 255) / 256, 256, 0, stream>>>(
        src, dst, ety, offs, rank, pedge);

    attp_kernel<<<(N_EDGES + 15) / 16, 256, 0, stream>>>(
        khp, q, relw, pedge, attp);
    agg_kernel<<<AGG_NB, 256, 0, stream>>>(
        offs, (const unsigned*)pedge, attp, (const unsigned short*)vhp,
        alpha, out, bnpart);
    bnfin_kernel<<<25, 256, 0, stream>>>(bnpart, gamma, beta, bnsc, bnsh);
    applyrout_kernel<<<2048 + (20000 + 255) / 256, 256, 0, stream>>>(
        out, bnsc, bnsh, rfeat, Wrw, Wrb);
}